// Round 5
// baseline (132.367 us; speedup 1.0000x reference)
//
#include <hip/hip_runtime.h>
#include <hip/hip_cooperative_groups.h>

namespace cg = cooperative_groups;

#define EPSF 1e-5f
#define KSTR 68    // attn K LDS row stride (floats)
#define PSTR 260   // attn P row stride (floats)

#define FMA4(ACC, ZS, WV) \
    ACC.x = fmaf(ZS, WV.x, ACC.x); ACC.y = fmaf(ZS, WV.y, ACC.y); \
    ACC.z = fmaf(ZS, WV.z, ACC.z); ACC.w = fmaf(ZS, WV.w, ACC.w);

// ---------------------------------------------------------------------------
// MEGA: all three R1-verified phase bodies in one cooperative kernel.
// 256 blocks x 512 threads, 1 block/CU (106 KB LDS), 2 grid syncs replace
// 2 kernel boundaries. Phase bodies are byte-for-byte the R1 winners:
//   A: patch embed + LN + NF + fused QKV (8 tokens/block, 4-way k-split)
//   B: AG-NFA attention v2 (K in LDS, V streamed, Q+NF in registers)
//   C: Wo GEMM + LE-fusion
// ---------------------------------------------------------------------------
__global__ __launch_bounds__(512, 2) void mega(
    const float* __restrict__ x,
    const float* __restrict__ Wp, const float* __restrict__ bp,
    const float* __restrict__ ln_g, const float* __restrict__ ln_b,
    const float* __restrict__ Wq, const float* __restrict__ bq,
    const float* __restrict__ Wk, const float* __restrict__ bk,
    const float* __restrict__ Wv, const float* __restrict__ bv,
    const float* __restrict__ Wo, const float* __restrict__ bo,
    float* __restrict__ Qg, float* __restrict__ Kg, float* __restrict__ Vg,
    float* __restrict__ Og, float* __restrict__ out)
{
    extern __shared__ float sm[];
    cg::grid_group grid = cg::this_grid();

    const int tid = threadIdx.x;
    const int bid = blockIdx.x;

    // =======================================================================
    // Phase A: patch embed + LN + NF + QKV  (R1 ka, verbatim)
    // =======================================================================
    {
        float* zr = sm;          // [8][256] patch rows, then z rows
        float* ps = sm + 2048;   // [3][4][8][256] partials

        const int kq = tid >> 7, tg = (tid >> 6) & 1, ln = tid & 63;
        const int wave = tid >> 6, lane = tid & 63;
        const int tok0 = bid * 8;
        const int tg4 = 4 * tg;

        // ---- stage 8 patches as rows ----
        #pragma unroll
        for (int i = 0; i < 4; ++i) {
            int e = tid + 512 * i;
            int t = e >> 8, dd = e & 255;
            int tk = tok0 + t, b = tk >> 8, n = tk & 255;
            int ph = n >> 4, pw = n & 15, p = dd >> 4, q = dd & 15;
            zr[t * 256 + dd] = x[b * 65536 + (ph * 16 + p) * 256 + pw * 16 + q];
        }
        __syncthreads();

        // ---- phase 0: z = patch @ Wp (8-deep k batches) ----
        {
            const float* wr = Wp + kq * 16384 + 4 * ln;
            const float* zb = zr + tg4 * 256 + kq * 64;
            float4 a0 = make_float4(0.f,0.f,0.f,0.f), a1 = a0, a2 = a0, a3 = a0;
            #pragma unroll
            for (int kk = 0; kk < 64; kk += 8) {
                float4 w0 = *(const float4*)(wr + (kk + 0) * 256);
                float4 w1 = *(const float4*)(wr + (kk + 1) * 256);
                float4 w2 = *(const float4*)(wr + (kk + 2) * 256);
                float4 w3 = *(const float4*)(wr + (kk + 3) * 256);
                float4 w4 = *(const float4*)(wr + (kk + 4) * 256);
                float4 w5 = *(const float4*)(wr + (kk + 5) * 256);
                float4 w6 = *(const float4*)(wr + (kk + 6) * 256);
                float4 w7 = *(const float4*)(wr + (kk + 7) * 256);
                float4 zA0 = *(const float4*)(zb + 0 * 256 + kk);
                float4 zA1 = *(const float4*)(zb + 0 * 256 + kk + 4);
                float4 zB0 = *(const float4*)(zb + 1 * 256 + kk);
                float4 zB1 = *(const float4*)(zb + 1 * 256 + kk + 4);
                float4 zC0 = *(const float4*)(zb + 2 * 256 + kk);
                float4 zC1 = *(const float4*)(zb + 2 * 256 + kk + 4);
                float4 zD0 = *(const float4*)(zb + 3 * 256 + kk);
                float4 zD1 = *(const float4*)(zb + 3 * 256 + kk + 4);
                FMA4(a0, zA0.x, w0) FMA4(a0, zA0.y, w1) FMA4(a0, zA0.z, w2) FMA4(a0, zA0.w, w3)
                FMA4(a0, zA1.x, w4) FMA4(a0, zA1.y, w5) FMA4(a0, zA1.z, w6) FMA4(a0, zA1.w, w7)
                FMA4(a1, zB0.x, w0) FMA4(a1, zB0.y, w1) FMA4(a1, zB0.z, w2) FMA4(a1, zB0.w, w3)
                FMA4(a1, zB1.x, w4) FMA4(a1, zB1.y, w5) FMA4(a1, zB1.z, w6) FMA4(a1, zB1.w, w7)
                FMA4(a2, zC0.x, w0) FMA4(a2, zC0.y, w1) FMA4(a2, zC0.z, w2) FMA4(a2, zC0.w, w3)
                FMA4(a2, zC1.x, w4) FMA4(a2, zC1.y, w5) FMA4(a2, zC1.z, w6) FMA4(a2, zC1.w, w7)
                FMA4(a3, zD0.x, w0) FMA4(a3, zD0.y, w1) FMA4(a3, zD0.z, w2) FMA4(a3, zD0.w, w3)
                FMA4(a3, zD1.x, w4) FMA4(a3, zD1.y, w5) FMA4(a3, zD1.z, w6) FMA4(a3, zD1.w, w7)
            }
            float* pp = ps + kq * 2048 + tg4 * 256 + 4 * ln;
            *(float4*)(pp + 0 * 256) = a0;
            *(float4*)(pp + 1 * 256) = a1;
            *(float4*)(pp + 2 * 256) = a2;
            *(float4*)(pp + 3 * 256) = a3;
        }
        __syncthreads();
        // combine z = sum of 4 k-partials + bias -> zr rows
        {
            int e = tid * 4;
            float4 u0 = *(float4*)(ps + e);
            float4 u1 = *(float4*)(ps + 2048 + e);
            float4 u2 = *(float4*)(ps + 4096 + e);
            float4 u3 = *(float4*)(ps + 6144 + e);
            float4 bb = *(const float4*)(bp + (e & 255));
            float4 z;
            z.x = (u0.x + u1.x) + (u2.x + u3.x) + bb.x;
            z.y = (u0.y + u1.y) + (u2.y + u3.y) + bb.y;
            z.z = (u0.z + u1.z) + (u2.z + u3.z) + bb.z;
            z.w = (u0.w + u1.w) + (u2.w + u3.w) + bb.w;
            *(float4*)(zr + e) = z;
        }
        __syncthreads();

        // ---- LN + NF: wave owns token `wave`; in-place on zr rows ----
        {
            float g[4], bb2[4], v[4];
            #pragma unroll
            for (int c = 0; c < 4; ++c) { g[c] = ln_g[lane + 64 * c]; bb2[c] = ln_b[lane + 64 * c]; }
            float s = 0.f, ss = 0.f;
            #pragma unroll
            for (int c = 0; c < 4; ++c) { v[c] = zr[wave * 256 + lane + 64 * c]; s += v[c]; ss += v[c] * v[c]; }
            #pragma unroll
            for (int o = 32; o; o >>= 1) { s += __shfl_xor(s, o); ss += __shfl_xor(ss, o); }
            float mu  = s * (1.f / 256.f);
            float var = ss * (1.f / 256.f) - mu * mu;
            float rs  = rsqrtf(var + EPSF);
            float zn[4]; float s2 = 0.f, ss2 = 0.f;
            #pragma unroll
            for (int c = 0; c < 4; ++c) {
                zn[c] = (v[c] - mu) * rs * g[c] + bb2[c];
                s2 += zn[c]; ss2 += zn[c] * zn[c];
            }
            #pragma unroll
            for (int o = 32; o; o >>= 1) { s2 += __shfl_xor(s2, o); ss2 += __shfl_xor(ss2, o); }
            float mu2  = s2 * (1.f / 256.f);
            float var2 = ss2 * (1.f / 256.f) - mu2 * mu2;
            float as = 0.f;
            #pragma unroll
            for (int c = 0; c < 4; ++c) as += fabsf(zn[c] - mu2);
            #pragma unroll
            for (int o = 32; o; o >>= 1) as += __shfl_xor(as, o);
            float nf = as / (sqrtf(var2 + EPSF) + EPSF);
            float sc = 1.f + nf;
            #pragma unroll
            for (int c = 0; c < 4; ++c) zr[wave * 256 + lane + 64 * c] = zn[c] * sc;
        }
        __syncthreads();

        // ---- phase 1: Q,K,V fused (4-deep k batches) ----
        {
            const float* qr = Wq + kq * 16384 + 4 * ln;
            const float* kr = Wk + kq * 16384 + 4 * ln;
            const float* vr = Wv + kq * 16384 + 4 * ln;
            const float* zb = zr + tg4 * 256 + kq * 64;
            float4 aq0 = make_float4(0.f,0.f,0.f,0.f), aq1 = aq0, aq2 = aq0, aq3 = aq0;
            float4 ak0 = aq0, ak1 = aq0, ak2 = aq0, ak3 = aq0;
            float4 av0 = aq0, av1 = aq0, av2 = aq0, av3 = aq0;
            #pragma unroll
            for (int kk = 0; kk < 64; kk += 4) {
                float4 qw0 = *(const float4*)(qr + (kk + 0) * 256);
                float4 qw1 = *(const float4*)(qr + (kk + 1) * 256);
                float4 qw2 = *(const float4*)(qr + (kk + 2) * 256);
                float4 qw3 = *(const float4*)(qr + (kk + 3) * 256);
                float4 kw0 = *(const float4*)(kr + (kk + 0) * 256);
                float4 kw1 = *(const float4*)(kr + (kk + 1) * 256);
                float4 kw2 = *(const float4*)(kr + (kk + 2) * 256);
                float4 kw3 = *(const float4*)(kr + (kk + 3) * 256);
                float4 vw0 = *(const float4*)(vr + (kk + 0) * 256);
                float4 vw1 = *(const float4*)(vr + (kk + 1) * 256);
                float4 vw2 = *(const float4*)(vr + (kk + 2) * 256);
                float4 vw3 = *(const float4*)(vr + (kk + 3) * 256);
                float4 zA = *(const float4*)(zb + 0 * 256 + kk);
                float4 zB = *(const float4*)(zb + 1 * 256 + kk);
                float4 zC = *(const float4*)(zb + 2 * 256 + kk);
                float4 zD = *(const float4*)(zb + 3 * 256 + kk);
                FMA4(aq0, zA.x, qw0) FMA4(aq0, zA.y, qw1) FMA4(aq0, zA.z, qw2) FMA4(aq0, zA.w, qw3)
                FMA4(ak0, zA.x, kw0) FMA4(ak0, zA.y, kw1) FMA4(ak0, zA.z, kw2) FMA4(ak0, zA.w, kw3)
                FMA4(av0, zA.x, vw0) FMA4(av0, zA.y, vw1) FMA4(av0, zA.z, vw2) FMA4(av0, zA.w, vw3)
                FMA4(aq1, zB.x, qw0) FMA4(aq1, zB.y, qw1) FMA4(aq1, zB.z, qw2) FMA4(aq1, zB.w, qw3)
                FMA4(ak1, zB.x, kw0) FMA4(ak1, zB.y, kw1) FMA4(ak1, zB.z, kw2) FMA4(ak1, zB.w, kw3)
                FMA4(av1, zB.x, vw0) FMA4(av1, zB.y, vw1) FMA4(av1, zB.z, vw2) FMA4(av1, zB.w, vw3)
                FMA4(aq2, zC.x, qw0) FMA4(aq2, zC.y, qw1) FMA4(aq2, zC.z, qw2) FMA4(aq2, zC.w, qw3)
                FMA4(ak2, zC.x, kw0) FMA4(ak2, zC.y, kw1) FMA4(ak2, zC.z, kw2) FMA4(ak2, zC.w, kw3)
                FMA4(av2, zC.x, vw0) FMA4(av2, zC.y, vw1) FMA4(av2, zC.z, vw2) FMA4(av2, zC.w, vw3)
                FMA4(aq3, zD.x, qw0) FMA4(aq3, zD.y, qw1) FMA4(aq3, zD.z, qw2) FMA4(aq3, zD.w, qw3)
                FMA4(ak3, zD.x, kw0) FMA4(ak3, zD.y, kw1) FMA4(ak3, zD.z, kw2) FMA4(ak3, zD.w, kw3)
                FMA4(av3, zD.x, vw0) FMA4(av3, zD.y, vw1) FMA4(av3, zD.z, vw2) FMA4(av3, zD.w, vw3)
            }
            float* pq = ps + kq * 2048 + tg4 * 256 + 4 * ln;
            *(float4*)(pq + 0 * 256) = aq0;
            *(float4*)(pq + 1 * 256) = aq1;
            *(float4*)(pq + 2 * 256) = aq2;
            *(float4*)(pq + 3 * 256) = aq3;
            float* pk = pq + 8192;
            *(float4*)(pk + 0 * 256) = ak0;
            *(float4*)(pk + 1 * 256) = ak1;
            *(float4*)(pk + 2 * 256) = ak2;
            *(float4*)(pk + 3 * 256) = ak3;
            float* pv = pq + 16384;
            *(float4*)(pv + 0 * 256) = av0;
            *(float4*)(pv + 1 * 256) = av1;
            *(float4*)(pv + 2 * 256) = av2;
            *(float4*)(pv + 3 * 256) = av3;
        }
        __syncthreads();

        // ---- combine + bias + write (B,NH,N,DH) ----
        {
            int e = tid * 4, t = e >> 8, d0 = e & 255;
            int tk = tok0 + t, b = tk >> 8, n = tk & 255;
            int h = d0 >> 6, dh = d0 & 63;
            #pragma unroll
            for (int mat = 0; mat < 3; ++mat) {
                const float* pr = ps + mat * 8192;
                float4 u0 = *(float4*)(pr + e);
                float4 u1 = *(float4*)(pr + 2048 + e);
                float4 u2 = *(float4*)(pr + 4096 + e);
                float4 u3 = *(float4*)(pr + 6144 + e);
                const float* bsrc = (mat == 0) ? bq : (mat == 1) ? bk : bv;
                float4 bb = *(const float4*)(bsrc + d0);
                float4 o;
                o.x = (u0.x + u1.x) + (u2.x + u3.x) + bb.x;
                o.y = (u0.y + u1.y) + (u2.y + u3.y) + bb.y;
                o.z = (u0.z + u1.z) + (u2.z + u3.z) + bb.z;
                o.w = (u0.w + u1.w) + (u2.w + u3.w) + bb.w;
                float* gout = ((mat == 0) ? Qg : (mat == 1) ? Kg : Vg)
                            + ((b * 4 + h) * 256 + n) * 64 + dh;
                *(float4*)gout = o;
            }
        }
    }

    grid.sync();

    // =======================================================================
    // Phase B: AG-NFA attention  (R1 kb v2, verbatim)
    // =======================================================================
    {
        float* Kl = sm;               // [256][KSTR]
        float* k2 = sm + 256 * KSTR;  // [256]
        float* Pl = sm;               // [32][PSTR] overlay after QK^T

        const int xcd = bid & 7, slot = bid >> 3;
        const int bh = xcd * 4 + (slot >> 3);
        const int qt = slot & 7;

        const float* Qb = Qg + (bh * 256 + qt * 32) * 64;
        const float* Kb = Kg + bh * 16384;
        const float* Vb = Vg + bh * 16384;

        const int q = tid >> 4;   // 0..31: query row
        const int r = tid & 15;   // 0..15

        // ---- stage K -> LDS (fully coalesced) ----
        {
            const float4* Ks = (const float4*)Kb;
            #pragma unroll
            for (int i = 0; i < 8; ++i) {
                int flat = tid + 512 * i;            // f4 index, 4096 total
                int row = flat >> 4, c4 = flat & 15;
                *(float4*)(Kl + row * KSTR + c4 * 4) = Ks[flat];
            }
        }
        __syncthreads();

        // ---- k2[m] = |K_m|^2 ----
        {
            int row = tid >> 1, half = tid & 1;
            const float* kp = Kl + row * KSTR + half * 32;
            float ssq = 0.f;
            #pragma unroll
            for (int c = 0; c < 8; ++c) {
                float4 kv = *(const float4*)(kp + 4 * c);
                ssq += kv.x*kv.x + kv.y*kv.y + kv.z*kv.z + kv.w*kv.w;
            }
            ssq += __shfl_xor(ssq, 1);
            if (half == 0) k2[row] = ssq;
        }

        // ---- Q row in registers + NF stats (thread-local) ----
        float4 Qr[16];
        {
            const float4* Qp = (const float4*)(Qb + q * 64);
            #pragma unroll
            for (int c = 0; c < 16; ++c) Qr[c] = Qp[c];
        }
        float fq, gq, iq;
        {
            float s = 0.f, ss = 0.f;
            #pragma unroll
            for (int c = 0; c < 16; ++c) {
                float4 v = Qr[c];
                s  += v.x + v.y + v.z + v.w;
                ss += v.x*v.x + v.y*v.y + v.z*v.z + v.w*v.w;
            }
            float mu = s * (1.f / 64.f);
            float as = 0.f;
            #pragma unroll
            for (int c = 0; c < 16; ++c) {
                float4 v = Qr[c];
                as += fabsf(v.x - mu) + fabsf(v.y - mu)
                    + fabsf(v.z - mu) + fabsf(v.w - mu);
            }
            float var = ss * (1.f / 64.f) - mu * mu;
            float sg  = sqrtf(var + EPSF);
            float nf  = as / (sg + EPSF);
            float inv = 1.f / (__expf(-nf) + 1.f);
            fq = 0.125f + 2.f * inv;
            gq = ss * inv;
            iq = inv;
        }
        __syncthreads();   // k2 visible

        // ---- QK^T: scores for m = r + 16j ----
        float s_[16];
        #pragma unroll
        for (int j = 0; j < 16; ++j) {
            int m = r + 16 * j;
            const float* kp = Kl + m * KSTR;
            float acc = 0.f;
            #pragma unroll
            for (int c = 0; c < 16; ++c) {
                float4 kv = *(const float4*)(kp + 4 * c);
                acc += Qr[c].x*kv.x + Qr[c].y*kv.y + Qr[c].z*kv.z + Qr[c].w*kv.w;
            }
            s_[j] = acc * fq - gq - k2[m] * iq;
        }

        // ---- softmax over m ----
        float M = s_[0];
        #pragma unroll
        for (int j = 1; j < 16; ++j) M = fmaxf(M, s_[j]);
        #pragma unroll
        for (int o = 1; o < 16; o <<= 1) M = fmaxf(M, __shfl_xor(M, o));
        float L = 0.f;
        #pragma unroll
        for (int j = 0; j < 16; ++j) { s_[j] = __expf(s_[j] - M); L += s_[j]; }
        #pragma unroll
        for (int o = 1; o < 16; o <<= 1) L += __shfl_xor(L, o);
        float invL = 1.f / L;

        __syncthreads();   // done reading Kl/k2 -> overlay Pl
        #pragma unroll
        for (int j = 0; j < 16; ++j) Pl[q * PSTR + r + 16 * j] = s_[j] * invL;
        __syncthreads();

        // ---- PV: thread owns d = 4r..4r+4; V rows streamed from global ----
        float4 a0 = make_float4(0.f, 0.f, 0.f, 0.f);
        const float* pq = Pl + q * PSTR;
        #pragma unroll 8
        for (int m = 0; m < 256; ++m) {
            float pw = pq[m];
            float4 v = *(const float4*)(Vb + m * 64 + 4 * r);
            a0.x = fmaf(pw, v.x, a0.x); a0.y = fmaf(pw, v.y, a0.y);
            a0.z = fmaf(pw, v.z, a0.z); a0.w = fmaf(pw, v.w, a0.w);
        }
        {
            int b = bh >> 2, h = bh & 3;
            int n = qt * 32 + q;
            float* op = Og + (b * 256 + n) * 256 + h * 64 + 4 * r;
            *(float4*)op = a0;
        }
    }

    grid.sync();

    // =======================================================================
    // Phase C: Wo GEMM + LE-fusion  (R1 kc, verbatim)
    // =======================================================================
    {
        float* yr  = sm;          // [8][256]
        float* ps  = sm + 2048;   // [4][8][256]
        float* red = sm + 10240;  // [8]

        const int kq = tid >> 7, tg = (tid >> 6) & 1, ln = tid & 63;
        const int wave = tid >> 6, lane = tid & 63;
        const int tok0 = bid * 8;
        const int tg4 = 4 * tg;

        *(float4*)(yr + tid * 4) = *(const float4*)(Og + tok0 * 256 + tid * 4);
        __syncthreads();

        {
            const float* wr = Wo + kq * 16384 + 4 * ln;
            const float* zb = yr + tg4 * 256 + kq * 64;
            float4 a0 = make_float4(0.f,0.f,0.f,0.f), a1 = a0, a2 = a0, a3 = a0;
            #pragma unroll
            for (int kk = 0; kk < 64; kk += 8) {
                float4 w0 = *(const float4*)(wr + (kk + 0) * 256);
                float4 w1 = *(const float4*)(wr + (kk + 1) * 256);
                float4 w2 = *(const float4*)(wr + (kk + 2) * 256);
                float4 w3 = *(const float4*)(wr + (kk + 3) * 256);
                float4 w4 = *(const float4*)(wr + (kk + 4) * 256);
                float4 w5 = *(const float4*)(wr + (kk + 5) * 256);
                float4 w6 = *(const float4*)(wr + (kk + 6) * 256);
                float4 w7 = *(const float4*)(wr + (kk + 7) * 256);
                float4 zA0 = *(const float4*)(zb + 0 * 256 + kk);
                float4 zA1 = *(const float4*)(zb + 0 * 256 + kk + 4);
                float4 zB0 = *(const float4*)(zb + 1 * 256 + kk);
                float4 zB1 = *(const float4*)(zb + 1 * 256 + kk + 4);
                float4 zC0 = *(const float4*)(zb + 2 * 256 + kk);
                float4 zC1 = *(const float4*)(zb + 2 * 256 + kk + 4);
                float4 zD0 = *(const float4*)(zb + 3 * 256 + kk);
                float4 zD1 = *(const float4*)(zb + 3 * 256 + kk + 4);
                FMA4(a0, zA0.x, w0) FMA4(a0, zA0.y, w1) FMA4(a0, zA0.z, w2) FMA4(a0, zA0.w, w3)
                FMA4(a0, zA1.x, w4) FMA4(a0, zA1.y, w5) FMA4(a0, zA1.z, w6) FMA4(a0, zA1.w, w7)
                FMA4(a1, zB0.x, w0) FMA4(a1, zB0.y, w1) FMA4(a1, zB0.z, w2) FMA4(a1, zB0.w, w3)
                FMA4(a1, zB1.x, w4) FMA4(a1, zB1.y, w5) FMA4(a1, zB1.z, w6) FMA4(a1, zB1.w, w7)
                FMA4(a2, zC0.x, w0) FMA4(a2, zC0.y, w1) FMA4(a2, zC0.z, w2) FMA4(a2, zC0.w, w3)
                FMA4(a2, zC1.x, w4) FMA4(a2, zC1.y, w5) FMA4(a2, zC1.z, w6) FMA4(a2, zC1.w, w7)
                FMA4(a3, zD0.x, w0) FMA4(a3, zD0.y, w1) FMA4(a3, zD0.z, w2) FMA4(a3, zD0.w, w3)
                FMA4(a3, zD1.x, w4) FMA4(a3, zD1.y, w5) FMA4(a3, zD1.z, w6) FMA4(a3, zD1.w, w7)
            }
            float* pp = ps + kq * 2048 + tg4 * 256 + 4 * ln;
            *(float4*)(pp + 0 * 256) = a0;
            *(float4*)(pp + 1 * 256) = a1;
            *(float4*)(pp + 2 * 256) = a2;
            *(float4*)(pp + 3 * 256) = a3;
        }
        __syncthreads();
        {
            int e = tid * 4;
            float4 u0 = *(float4*)(ps + e);
            float4 u1 = *(float4*)(ps + 2048 + e);
            float4 u2 = *(float4*)(ps + 4096 + e);
            float4 u3 = *(float4*)(ps + 6144 + e);
            float4 bb = *(const float4*)(bo + (e & 255));
            float4 y;
            y.x = (u0.x + u1.x) + (u2.x + u3.x) + bb.x;
            y.y = (u0.y + u1.y) + (u2.y + u3.y) + bb.y;
            y.z = (u0.z + u1.z) + (u2.z + u3.z) + bb.z;
            y.w = (u0.w + u1.w) + (u2.w + u3.w) + bb.w;
            *(float4*)(yr + e) = y;
        }
        __syncthreads();
        {
            float ssq = 0.f;
            #pragma unroll
            for (int c = 0; c < 4; ++c) {
                float v = yr[wave * 256 + lane + 64 * c];
                ssq += v * v;
            }
            #pragma unroll
            for (int o = 32; o; o >>= 1) ssq += __shfl_xor(ssq, o);
            if (lane == 0) red[wave] = sqrtf(ssq);
        }
        __syncthreads();
        {
            int g = tid >> 8, d = tid & 255;
            float e0 = red[4 * g], e1 = red[4 * g + 1], e2 = red[4 * g + 2], e3 = red[4 * g + 3];
            float m = fmaxf(fmaxf(e0, e1), fmaxf(e2, e3));
            float x0 = __expf(e0 - m), x1 = __expf(e1 - m), x2 = __expf(e2 - m), x3 = __expf(e3 - m);
            float inv = 1.f / (x0 + x1 + x2 + x3);
            float val = (x0 * yr[(4 * g) * 256 + d] + x1 * yr[(4 * g + 1) * 256 + d]
                       + x2 * yr[(4 * g + 2) * 256 + d] + x3 * yr[(4 * g + 3) * 256 + d]) * inv;
            out[(bid * 2 + g) * 256 + d] = val;
        }
    }
}

// ---------------------------------------------------------------------------
extern "C" void kernel_launch(void* const* d_in, const int* in_sizes, int n_in,
                              void* d_out, int out_size, void* d_ws, size_t ws_size,
                              hipStream_t stream) {
    const float* x    = (const float*)d_in[0];
    const float* Wp   = (const float*)d_in[1];
    const float* bp   = (const float*)d_in[2];
    const float* ln_g = (const float*)d_in[3];
    const float* ln_b = (const float*)d_in[4];
    const float* Wq   = (const float*)d_in[5];
    const float* bq   = (const float*)d_in[6];
    const float* Wk   = (const float*)d_in[7];
    const float* bk   = (const float*)d_in[8];
    const float* Wv   = (const float*)d_in[9];
    const float* bv   = (const float*)d_in[10];
    const float* Wo   = (const float*)d_in[11];
    const float* bo   = (const float*)d_in[12];
    float* out = (float*)d_out;

    float* ws = (float*)d_ws;
    float* Qg = ws;
    float* Kg = ws + 524288;
    float* Vg = ws + 524288 * 2;
    float* Og = ws + 524288 * 3;

    const int lds_bytes = (2048 + 3 * 4 * 2048) * 4;   // 106496 B (phase A max)
    (void)hipFuncSetAttribute((const void*)mega,
                              hipFuncAttributeMaxDynamicSharedMemorySize, lds_bytes);

    void* args[] = {
        (void*)&x, (void*)&Wp, (void*)&bp, (void*)&ln_g, (void*)&ln_b,
        (void*)&Wq, (void*)&bq, (void*)&Wk, (void*)&bk, (void*)&Wv, (void*)&bv,
        (void*)&Wo, (void*)&bo,
        (void*)&Qg, (void*)&Kg, (void*)&Vg, (void*)&Og, (void*)&out
    };
    (void)hipLaunchCooperativeKernel((const void*)mega, dim3(256), dim3(512),
                                     args, lds_bytes, stream);
}

// Round 6
// 57.476 us; speedup vs baseline: 2.3030x; 2.3030x over previous
//
#include <hip/hip_runtime.h>

#define EPSF 1e-5f
#define KSTR 68    // kb K LDS row stride (floats)
#define PSTR 260   // kb P row stride (floats)

#define FMA4(ACC, ZS, WV) \
    ACC.x = fmaf(ZS, WV.x, ACC.x); ACC.y = fmaf(ZS, WV.y, ACC.y); \
    ACC.z = fmaf(ZS, WV.z, ACC.z); ACC.w = fmaf(ZS, WV.w, ACC.w);

// ---------------------------------------------------------------------------
// GEMM pass, 8-token/thread form: thread (kq=tid>>6 in [0,8), ln=tid&63)
// owns k-rows [32kq,32kq+32), ALL 8 tokens, dims [4ln,4ln+4).
// Per-thread weight loads HALVED vs the 4-token form (32 f4 vs 64) at the
// same FMA count -> VMEM:VALU instruction ratio 1:32 (was 1:16).
// Partials ps[kq][tok][256] (64 KB), combined 8-way by the caller.
// ---------------------------------------------------------------------------
__device__ __forceinline__ void pass8x8(
    const float* __restrict__ W, const float* __restrict__ zr,
    float* __restrict__ ps, int kq, int ln)
{
    const float* wr = W + kq * 8192 + 4 * ln;    // k-row base
    const float* zb = zr + kq * 32;
    float4 a0 = make_float4(0.f,0.f,0.f,0.f), a1 = a0, a2 = a0, a3 = a0;
    float4 a4 = a0, a5 = a0, a6 = a0, a7 = a0;
    #pragma unroll
    for (int kk = 0; kk < 32; kk += 4) {
        float4 w0 = *(const float4*)(wr + (kk + 0) * 256);
        float4 w1 = *(const float4*)(wr + (kk + 1) * 256);
        float4 w2 = *(const float4*)(wr + (kk + 2) * 256);
        float4 w3 = *(const float4*)(wr + (kk + 3) * 256);
        float4 z0 = *(const float4*)(zb + 0 * 256 + kk);
        float4 z1 = *(const float4*)(zb + 1 * 256 + kk);
        float4 z2 = *(const float4*)(zb + 2 * 256 + kk);
        float4 z3 = *(const float4*)(zb + 3 * 256 + kk);
        float4 z4 = *(const float4*)(zb + 4 * 256 + kk);
        float4 z5 = *(const float4*)(zb + 5 * 256 + kk);
        float4 z6 = *(const float4*)(zb + 6 * 256 + kk);
        float4 z7 = *(const float4*)(zb + 7 * 256 + kk);
        FMA4(a0, z0.x, w0) FMA4(a0, z0.y, w1) FMA4(a0, z0.z, w2) FMA4(a0, z0.w, w3)
        FMA4(a1, z1.x, w0) FMA4(a1, z1.y, w1) FMA4(a1, z1.z, w2) FMA4(a1, z1.w, w3)
        FMA4(a2, z2.x, w0) FMA4(a2, z2.y, w1) FMA4(a2, z2.z, w2) FMA4(a2, z2.w, w3)
        FMA4(a3, z3.x, w0) FMA4(a3, z3.y, w1) FMA4(a3, z3.z, w2) FMA4(a3, z3.w, w3)
        FMA4(a4, z4.x, w0) FMA4(a4, z4.y, w1) FMA4(a4, z4.z, w2) FMA4(a4, z4.w, w3)
        FMA4(a5, z5.x, w0) FMA4(a5, z5.y, w1) FMA4(a5, z5.z, w2) FMA4(a5, z5.w, w3)
        FMA4(a6, z6.x, w0) FMA4(a6, z6.y, w1) FMA4(a6, z6.z, w2) FMA4(a6, z6.w, w3)
        FMA4(a7, z7.x, w0) FMA4(a7, z7.y, w1) FMA4(a7, z7.z, w2) FMA4(a7, z7.w, w3)
    }
    float* pp = ps + kq * 2048 + 4 * ln;
    *(float4*)(pp + 0 * 256) = a0;
    *(float4*)(pp + 1 * 256) = a1;
    *(float4*)(pp + 2 * 256) = a2;
    *(float4*)(pp + 3 * 256) = a3;
    *(float4*)(pp + 4 * 256) = a4;
    *(float4*)(pp + 5 * 256) = a5;
    *(float4*)(pp + 6 * 256) = a6;
    *(float4*)(pp + 7 * 256) = a7;
}

__device__ __forceinline__ float4 combine8(const float* __restrict__ ps, int e)
{
    float4 a = *(const float4*)(ps + e);
    #pragma unroll
    for (int k = 1; k < 8; ++k) {
        float4 u = *(const float4*)(ps + k * 2048 + e);
        a.x += u.x; a.y += u.y; a.z += u.z; a.w += u.w;
    }
    return a;
}

// ---------------------------------------------------------------------------
// KA: patch embed + LN + NF + QKV. 256 blocks x 512 threads, 8 tokens/block.
// 8-way k-split, 8 tokens/thread (no weight duplication). QKV = 3 sequential
// passes reusing one 64 KB ps (keeps VGPR ~110, no spills).
// ---------------------------------------------------------------------------
__global__ __launch_bounds__(512, 2) void ka_patch_nf_qkv(
    const float* __restrict__ x,
    const float* __restrict__ Wp, const float* __restrict__ bp,
    const float* __restrict__ ln_g, const float* __restrict__ ln_b,
    const float* __restrict__ Wq, const float* __restrict__ bq,
    const float* __restrict__ Wk, const float* __restrict__ bk,
    const float* __restrict__ Wv, const float* __restrict__ bv,
    float* __restrict__ Qg, float* __restrict__ Kg, float* __restrict__ Vg)
{
    extern __shared__ float sm[];
    float* zr = sm;          // [8][256] patch rows, then z rows
    float* ps = sm + 2048;   // [8][8][256] k-partials (64 KB)

    const int tid = threadIdx.x;
    const int kq = tid >> 6, ln = tid & 63;
    const int wave = tid >> 6, lane = tid & 63;
    const int tok0 = blockIdx.x * 8;

    // ---- stage 8 patches as rows ----
    #pragma unroll
    for (int i = 0; i < 4; ++i) {
        int e = tid + 512 * i;
        int t = e >> 8, dd = e & 255;
        int tk = tok0 + t, b = tk >> 8, n = tk & 255;
        int ph = n >> 4, pw = n & 15, p = dd >> 4, q = dd & 15;
        zr[t * 256 + dd] = x[b * 65536 + (ph * 16 + p) * 256 + pw * 16 + q];
    }
    __syncthreads();

    // ---- z = patch @ Wp ----
    pass8x8(Wp, zr, ps, kq, ln);
    __syncthreads();
    {
        int e = tid * 4;
        float4 a = combine8(ps, e);
        float4 bb = *(const float4*)(bp + (e & 255));
        a.x += bb.x; a.y += bb.y; a.z += bb.z; a.w += bb.w;
        *(float4*)(zr + e) = a;
    }
    __syncthreads();

    // ---- LN + NF: wave owns token `wave`; in-place on zr rows ----
    {
        float g[4], bb2[4], v[4];
        #pragma unroll
        for (int c = 0; c < 4; ++c) { g[c] = ln_g[lane + 64 * c]; bb2[c] = ln_b[lane + 64 * c]; }
        float s = 0.f, ss = 0.f;
        #pragma unroll
        for (int c = 0; c < 4; ++c) { v[c] = zr[wave * 256 + lane + 64 * c]; s += v[c]; ss += v[c] * v[c]; }
        #pragma unroll
        for (int o = 32; o; o >>= 1) { s += __shfl_xor(s, o); ss += __shfl_xor(ss, o); }
        float mu  = s * (1.f / 256.f);
        float var = ss * (1.f / 256.f) - mu * mu;
        float rs  = rsqrtf(var + EPSF);
        float zn[4]; float s2 = 0.f, ss2 = 0.f;
        #pragma unroll
        for (int c = 0; c < 4; ++c) {
            zn[c] = (v[c] - mu) * rs * g[c] + bb2[c];
            s2 += zn[c]; ss2 += zn[c] * zn[c];
        }
        #pragma unroll
        for (int o = 32; o; o >>= 1) { s2 += __shfl_xor(s2, o); ss2 += __shfl_xor(ss2, o); }
        float mu2  = s2 * (1.f / 256.f);
        float var2 = ss2 * (1.f / 256.f) - mu2 * mu2;
        float as = 0.f;
        #pragma unroll
        for (int c = 0; c < 4; ++c) as += fabsf(zn[c] - mu2);
        #pragma unroll
        for (int o = 32; o; o >>= 1) as += __shfl_xor(as, o);
        float nf = as / (sqrtf(var2 + EPSF) + EPSF);
        float sc = 1.f + nf;
        #pragma unroll
        for (int c = 0; c < 4; ++c) zr[wave * 256 + lane + 64 * c] = zn[c] * sc;
    }
    __syncthreads();

    // ---- Q, K, V passes ----
    {
        int e = tid * 4, t = e >> 8, d0 = e & 255;
        int tk = tok0 + t, b = tk >> 8, n = tk & 255;
        int h = d0 >> 6, dh = d0 & 63;
        const long goff = ((long)(b * 4 + h) * 256 + n) * 64 + dh;

        pass8x8(Wq, zr, ps, kq, ln);
        __syncthreads();
        {
            float4 a = combine8(ps, e);
            float4 bb = *(const float4*)(bq + d0);
            a.x += bb.x; a.y += bb.y; a.z += bb.z; a.w += bb.w;
            *(float4*)(Qg + goff) = a;
        }
        __syncthreads();

        pass8x8(Wk, zr, ps, kq, ln);
        __syncthreads();
        {
            float4 a = combine8(ps, e);
            float4 bb = *(const float4*)(bk + d0);
            a.x += bb.x; a.y += bb.y; a.z += bb.z; a.w += bb.w;
            *(float4*)(Kg + goff) = a;
        }
        __syncthreads();

        pass8x8(Wv, zr, ps, kq, ln);
        __syncthreads();
        {
            float4 a = combine8(ps, e);
            float4 bb = *(const float4*)(bv + d0);
            a.x += bb.x; a.y += bb.y; a.z += bb.z; a.w += bb.w;
            *(float4*)(Vg + goff) = a;
        }
    }
}

// ---------------------------------------------------------------------------
// KB v2: AG-NFA attention — EXACT R1 form (verified winner). 512 threads.
// K staged in LDS; V streamed from global; Q row + NF stats in registers.
// ---------------------------------------------------------------------------
__global__ __launch_bounds__(512, 2) void kb_attn(
    const float* __restrict__ Qg, const float* __restrict__ Kg,
    const float* __restrict__ Vg, float* __restrict__ Og)
{
    extern __shared__ float lds[];
    float* Kl = lds;               // [256][KSTR]
    float* k2 = lds + 256 * KSTR;  // [256]
    float* Pl = lds;               // [32][PSTR] overlay on Kl after QK^T

    const int tid = threadIdx.x;
    const int xcd = blockIdx.x & 7, slot = blockIdx.x >> 3;
    const int bh = xcd * 4 + (slot >> 3);
    const int qt = slot & 7;

    const float* Qb = Qg + (bh * 256 + qt * 32) * 64;
    const float* Kb = Kg + bh * 16384;
    const float* Vb = Vg + bh * 16384;

    const int q = tid >> 4;   // 0..31: query row
    const int r = tid & 15;   // 0..15

    // ---- stage K -> LDS (fully coalesced) ----
    {
        const float4* Ks = (const float4*)Kb;
        #pragma unroll
        for (int i = 0; i < 8; ++i) {
            int flat = tid + 512 * i;            // f4 index, 4096 total
            int row = flat >> 4, c4 = flat & 15;
            *(float4*)(Kl + row * KSTR + c4 * 4) = Ks[flat];
        }
    }
    __syncthreads();

    // ---- k2[m] = |K_m|^2 ----
    {
        int row = tid >> 1, half = tid & 1;
        const float* kp = Kl + row * KSTR + half * 32;
        float ssq = 0.f;
        #pragma unroll
        for (int c = 0; c < 8; ++c) {
            float4 kv = *(const float4*)(kp + 4 * c);
            ssq += kv.x*kv.x + kv.y*kv.y + kv.z*kv.z + kv.w*kv.w;
        }
        ssq += __shfl_xor(ssq, 1);
        if (half == 0) k2[row] = ssq;
    }

    // ---- Q row in registers + NF stats (thread-local) ----
    float4 Qr[16];
    {
        const float4* Qp = (const float4*)(Qb + q * 64);
        #pragma unroll
        for (int c = 0; c < 16; ++c) Qr[c] = Qp[c];
    }
    float fq, gq, iq;
    {
        float s = 0.f, ss = 0.f;
        #pragma unroll
        for (int c = 0; c < 16; ++c) {
            float4 v = Qr[c];
            s  += v.x + v.y + v.z + v.w;
            ss += v.x*v.x + v.y*v.y + v.z*v.z + v.w*v.w;
        }
        float mu = s * (1.f / 64.f);
        float as = 0.f;
        #pragma unroll
        for (int c = 0; c < 16; ++c) {
            float4 v = Qr[c];
            as += fabsf(v.x - mu) + fabsf(v.y - mu)
                + fabsf(v.z - mu) + fabsf(v.w - mu);
        }
        float var = ss * (1.f / 64.f) - mu * mu;
        float sg  = sqrtf(var + EPSF);
        float nf  = as / (sg + EPSF);
        float inv = 1.f / (__expf(-nf) + 1.f);
        fq = 0.125f + 2.f * inv;
        gq = ss * inv;
        iq = inv;
    }
    __syncthreads();   // k2 visible

    // ---- QK^T: scores for m = r + 16j ----
    float s_[16];
    #pragma unroll
    for (int j = 0; j < 16; ++j) {
        int m = r + 16 * j;
        const float* kp = Kl + m * KSTR;
        float acc = 0.f;
        #pragma unroll
        for (int c = 0; c < 16; ++c) {
            float4 kv = *(const float4*)(kp + 4 * c);
            acc += Qr[c].x*kv.x + Qr[c].y*kv.y + Qr[c].z*kv.z + Qr[c].w*kv.w;
        }
        s_[j] = acc * fq - gq - k2[m] * iq;
    }

    // ---- softmax over m ----
    float M = s_[0];
    #pragma unroll
    for (int j = 1; j < 16; ++j) M = fmaxf(M, s_[j]);
    #pragma unroll
    for (int o = 1; o < 16; o <<= 1) M = fmaxf(M, __shfl_xor(M, o));
    float L = 0.f;
    #pragma unroll
    for (int j = 0; j < 16; ++j) { s_[j] = __expf(s_[j] - M); L += s_[j]; }
    #pragma unroll
    for (int o = 1; o < 16; o <<= 1) L += __shfl_xor(L, o);
    float invL = 1.f / L;

    __syncthreads();   // done reading Kl/k2 -> overlay Pl
    #pragma unroll
    for (int j = 0; j < 16; ++j) Pl[q * PSTR + r + 16 * j] = s_[j] * invL;
    __syncthreads();

    // ---- PV: thread owns d = 4r..4r+4; V rows streamed from global ----
    float4 a0 = make_float4(0.f, 0.f, 0.f, 0.f);
    const float* pq = Pl + q * PSTR;
    #pragma unroll 8
    for (int m = 0; m < 256; ++m) {
        float pw = pq[m];
        float4 v = *(const float4*)(Vb + m * 64 + 4 * r);
        a0.x = fmaf(pw, v.x, a0.x); a0.y = fmaf(pw, v.y, a0.y);
        a0.z = fmaf(pw, v.z, a0.z); a0.w = fmaf(pw, v.w, a0.w);
    }
    {
        int b = bh >> 2, h = bh & 3;
        int n = qt * 32 + q;
        float* op = Og + (b * 256 + n) * 256 + h * 64 + 4 * r;
        *(float4*)op = a0;
    }
}

// ---------------------------------------------------------------------------
// KC: Y = attn_out @ Wo + bo, then LE-fusion. 8-way k-split, 8 tok/thread
// (same VMEM-halving treatment as KA). 256 blocks x 512 threads.
// ---------------------------------------------------------------------------
__global__ __launch_bounds__(512, 2) void kc_wo_le(
    const float* __restrict__ Og, const float* __restrict__ Wo,
    const float* __restrict__ bo, float* __restrict__ out)
{
    extern __shared__ float sm[];
    float* yr  = sm;           // [8][256]
    float* ps  = sm + 2048;    // [8][8][256] (64 KB)
    float* red = sm + 18432;   // [8]

    const int tid = threadIdx.x;
    const int kq = tid >> 6, ln = tid & 63;
    const int wave = tid >> 6, lane = tid & 63;
    const int tok0 = blockIdx.x * 8;

    *(float4*)(yr + tid * 4) = *(const float4*)(Og + tok0 * 256 + tid * 4);
    __syncthreads();

    pass8x8(Wo, yr, ps, kq, ln);
    __syncthreads();
    {
        int e = tid * 4;
        float4 a = combine8(ps, e);
        float4 bb = *(const float4*)(bo + (e & 255));
        a.x += bb.x; a.y += bb.y; a.z += bb.z; a.w += bb.w;
        *(float4*)(yr + e) = a;
    }
    __syncthreads();
    // per-token ||Y||: wave owns token `wave`
    {
        float ssq = 0.f;
        #pragma unroll
        for (int c = 0; c < 4; ++c) {
            float v = yr[wave * 256 + lane + 64 * c];
            ssq += v * v;
        }
        #pragma unroll
        for (int o = 32; o; o >>= 1) ssq += __shfl_xor(ssq, o);
        if (lane == 0) red[wave] = sqrtf(ssq);
    }
    __syncthreads();
    // LE-fusion
    {
        int g = tid >> 8, d = tid & 255;
        float e0 = red[4 * g], e1 = red[4 * g + 1], e2 = red[4 * g + 2], e3 = red[4 * g + 3];
        float m = fmaxf(fmaxf(e0, e1), fmaxf(e2, e3));
        float x0 = __expf(e0 - m), x1 = __expf(e1 - m), x2 = __expf(e2 - m), x3 = __expf(e3 - m);
        float inv = 1.f / (x0 + x1 + x2 + x3);
        float val = (x0 * yr[(4 * g) * 256 + d] + x1 * yr[(4 * g + 1) * 256 + d]
                   + x2 * yr[(4 * g + 2) * 256 + d] + x3 * yr[(4 * g + 3) * 256 + d]) * inv;
        out[(blockIdx.x * 2 + g) * 256 + d] = val;
    }
}

// ---------------------------------------------------------------------------
extern "C" void kernel_launch(void* const* d_in, const int* in_sizes, int n_in,
                              void* d_out, int out_size, void* d_ws, size_t ws_size,
                              hipStream_t stream) {
    const float* x    = (const float*)d_in[0];
    const float* Wp   = (const float*)d_in[1];
    const float* bp   = (const float*)d_in[2];
    const float* ln_g = (const float*)d_in[3];
    const float* ln_b = (const float*)d_in[4];
    const float* Wq   = (const float*)d_in[5];
    const float* bq   = (const float*)d_in[6];
    const float* Wk   = (const float*)d_in[7];
    const float* bk   = (const float*)d_in[8];
    const float* Wv   = (const float*)d_in[9];
    const float* bv   = (const float*)d_in[10];
    const float* Wo   = (const float*)d_in[11];
    const float* bo   = (const float*)d_in[12];
    float* out = (float*)d_out;

    float* ws = (float*)d_ws;
    float* Qg = ws;
    float* Kg = ws + 524288;
    float* Vg = ws + 524288 * 2;
    float* Og = ws + 524288 * 3;

    const int ka_lds = (2048 + 16384) * 4;          // 73728 B
    const int kb_lds = (256 * KSTR + 256) * 4;      // 70656 B
    const int kc_lds = (2048 + 16384 + 8) * 4;      // 73760 B
    (void)hipFuncSetAttribute((const void*)ka_patch_nf_qkv,
                              hipFuncAttributeMaxDynamicSharedMemorySize, ka_lds);
    (void)hipFuncSetAttribute((const void*)kb_attn,
                              hipFuncAttributeMaxDynamicSharedMemorySize, kb_lds);
    (void)hipFuncSetAttribute((const void*)kc_wo_le,
                              hipFuncAttributeMaxDynamicSharedMemorySize, kc_lds);

    ka_patch_nf_qkv<<<256, 512, ka_lds, stream>>>(x, Wp, bp, ln_g, ln_b,
                                                  Wq, bq, Wk, bk, Wv, bv, Qg, Kg, Vg);
    kb_attn<<<256, 512, kb_lds, stream>>>(Qg, Kg, Vg, Og);
    kc_wo_le<<<256, 512, kc_lds, stream>>>(Og, Wo, bo, out);
}

// Round 7
// 49.915 us; speedup vs baseline: 2.6519x; 1.1515x over previous
//
#include <hip/hip_runtime.h>

#define EPSF 1e-5f
#define KSTR 68    // kb K/V LDS row stride (floats)
#define PSTR 260   // kb P row stride (floats)

#define FMA4(ACC, ZS, WV) \
    ACC.x = fmaf(ZS, WV.x, ACC.x); ACC.y = fmaf(ZS, WV.y, ACC.y); \
    ACC.z = fmaf(ZS, WV.z, ACC.z); ACC.w = fmaf(ZS, WV.w, ACC.w);

// ---------------------------------------------------------------------------
// GEMM pass, 8-token/thread form: thread (kq=tid>>6 in [0,8), ln=tid&63)
// owns k-rows [32kq,32kq+32), ALL 8 tokens, dims [4ln,4ln+4).
// VMEM:VALU instruction ratio 1:32. Partials ps[kq][tok][256] (64 KB).
// [R6-verified]
// ---------------------------------------------------------------------------
__device__ __forceinline__ void pass8x8(
    const float* __restrict__ W, const float* __restrict__ zr,
    float* __restrict__ ps, int kq, int ln)
{
    const float* wr = W + kq * 8192 + 4 * ln;    // k-row base
    const float* zb = zr + kq * 32;
    float4 a0 = make_float4(0.f,0.f,0.f,0.f), a1 = a0, a2 = a0, a3 = a0;
    float4 a4 = a0, a5 = a0, a6 = a0, a7 = a0;
    #pragma unroll
    for (int kk = 0; kk < 32; kk += 4) {
        float4 w0 = *(const float4*)(wr + (kk + 0) * 256);
        float4 w1 = *(const float4*)(wr + (kk + 1) * 256);
        float4 w2 = *(const float4*)(wr + (kk + 2) * 256);
        float4 w3 = *(const float4*)(wr + (kk + 3) * 256);
        float4 z0 = *(const float4*)(zb + 0 * 256 + kk);
        float4 z1 = *(const float4*)(zb + 1 * 256 + kk);
        float4 z2 = *(const float4*)(zb + 2 * 256 + kk);
        float4 z3 = *(const float4*)(zb + 3 * 256 + kk);
        float4 z4 = *(const float4*)(zb + 4 * 256 + kk);
        float4 z5 = *(const float4*)(zb + 5 * 256 + kk);
        float4 z6 = *(const float4*)(zb + 6 * 256 + kk);
        float4 z7 = *(const float4*)(zb + 7 * 256 + kk);
        FMA4(a0, z0.x, w0) FMA4(a0, z0.y, w1) FMA4(a0, z0.z, w2) FMA4(a0, z0.w, w3)
        FMA4(a1, z1.x, w0) FMA4(a1, z1.y, w1) FMA4(a1, z1.z, w2) FMA4(a1, z1.w, w3)
        FMA4(a2, z2.x, w0) FMA4(a2, z2.y, w1) FMA4(a2, z2.z, w2) FMA4(a2, z2.w, w3)
        FMA4(a3, z3.x, w0) FMA4(a3, z3.y, w1) FMA4(a3, z3.z, w2) FMA4(a3, z3.w, w3)
        FMA4(a4, z4.x, w0) FMA4(a4, z4.y, w1) FMA4(a4, z4.z, w2) FMA4(a4, z4.w, w3)
        FMA4(a5, z5.x, w0) FMA4(a5, z5.y, w1) FMA4(a5, z5.z, w2) FMA4(a5, z5.w, w3)
        FMA4(a6, z6.x, w0) FMA4(a6, z6.y, w1) FMA4(a6, z6.z, w2) FMA4(a6, z6.w, w3)
        FMA4(a7, z7.x, w0) FMA4(a7, z7.y, w1) FMA4(a7, z7.z, w2) FMA4(a7, z7.w, w3)
    }
    float* pp = ps + kq * 2048 + 4 * ln;
    *(float4*)(pp + 0 * 256) = a0;
    *(float4*)(pp + 1 * 256) = a1;
    *(float4*)(pp + 2 * 256) = a2;
    *(float4*)(pp + 3 * 256) = a3;
    *(float4*)(pp + 4 * 256) = a4;
    *(float4*)(pp + 5 * 256) = a5;
    *(float4*)(pp + 6 * 256) = a6;
    *(float4*)(pp + 7 * 256) = a7;
}

__device__ __forceinline__ float4 combine8(const float* __restrict__ ps, int e)
{
    float4 a = *(const float4*)(ps + e);
    #pragma unroll
    for (int k = 1; k < 8; ++k) {
        float4 u = *(const float4*)(ps + k * 2048 + e);
        a.x += u.x; a.y += u.y; a.z += u.z; a.w += u.w;
    }
    return a;
}

// ---------------------------------------------------------------------------
// KA: patch embed + LN + NF + QKV. 256 blocks x 512 threads. [R6-verified]
// ---------------------------------------------------------------------------
__global__ __launch_bounds__(512, 2) void ka_patch_nf_qkv(
    const float* __restrict__ x,
    const float* __restrict__ Wp, const float* __restrict__ bp,
    const float* __restrict__ ln_g, const float* __restrict__ ln_b,
    const float* __restrict__ Wq, const float* __restrict__ bq,
    const float* __restrict__ Wk, const float* __restrict__ bk,
    const float* __restrict__ Wv, const float* __restrict__ bv,
    float* __restrict__ Qg, float* __restrict__ Kg, float* __restrict__ Vg)
{
    extern __shared__ float sm[];
    float* zr = sm;          // [8][256] patch rows, then z rows
    float* ps = sm + 2048;   // [8][8][256] k-partials (64 KB)

    const int tid = threadIdx.x;
    const int kq = tid >> 6, ln = tid & 63;
    const int wave = tid >> 6, lane = tid & 63;
    const int tok0 = blockIdx.x * 8;

    // ---- stage 8 patches as rows ----
    #pragma unroll
    for (int i = 0; i < 4; ++i) {
        int e = tid + 512 * i;
        int t = e >> 8, dd = e & 255;
        int tk = tok0 + t, b = tk >> 8, n = tk & 255;
        int ph = n >> 4, pw = n & 15, p = dd >> 4, q = dd & 15;
        zr[t * 256 + dd] = x[b * 65536 + (ph * 16 + p) * 256 + pw * 16 + q];
    }
    __syncthreads();

    // ---- z = patch @ Wp ----
    pass8x8(Wp, zr, ps, kq, ln);
    __syncthreads();
    {
        int e = tid * 4;
        float4 a = combine8(ps, e);
        float4 bb = *(const float4*)(bp + (e & 255));
        a.x += bb.x; a.y += bb.y; a.z += bb.z; a.w += bb.w;
        *(float4*)(zr + e) = a;
    }
    __syncthreads();

    // ---- LN + NF: wave owns token `wave`; in-place on zr rows ----
    {
        float g[4], bb2[4], v[4];
        #pragma unroll
        for (int c = 0; c < 4; ++c) { g[c] = ln_g[lane + 64 * c]; bb2[c] = ln_b[lane + 64 * c]; }
        float s = 0.f, ss = 0.f;
        #pragma unroll
        for (int c = 0; c < 4; ++c) { v[c] = zr[wave * 256 + lane + 64 * c]; s += v[c]; ss += v[c] * v[c]; }
        #pragma unroll
        for (int o = 32; o; o >>= 1) { s += __shfl_xor(s, o); ss += __shfl_xor(ss, o); }
        float mu  = s * (1.f / 256.f);
        float var = ss * (1.f / 256.f) - mu * mu;
        float rs  = rsqrtf(var + EPSF);
        float zn[4]; float s2 = 0.f, ss2 = 0.f;
        #pragma unroll
        for (int c = 0; c < 4; ++c) {
            zn[c] = (v[c] - mu) * rs * g[c] + bb2[c];
            s2 += zn[c]; ss2 += zn[c] * zn[c];
        }
        #pragma unroll
        for (int o = 32; o; o >>= 1) { s2 += __shfl_xor(s2, o); ss2 += __shfl_xor(ss2, o); }
        float mu2  = s2 * (1.f / 256.f);
        float var2 = ss2 * (1.f / 256.f) - mu2 * mu2;
        float as = 0.f;
        #pragma unroll
        for (int c = 0; c < 4; ++c) as += fabsf(zn[c] - mu2);
        #pragma unroll
        for (int o = 32; o; o >>= 1) as += __shfl_xor(as, o);
        float nf = as / (sqrtf(var2 + EPSF) + EPSF);
        float sc = 1.f + nf;
        #pragma unroll
        for (int c = 0; c < 4; ++c) zr[wave * 256 + lane + 64 * c] = zn[c] * sc;
    }
    __syncthreads();

    // ---- Q, K, V passes ----
    {
        int e = tid * 4, t = e >> 8, d0 = e & 255;
        int tk = tok0 + t, b = tk >> 8, n = tk & 255;
        int h = d0 >> 6, dh = d0 & 63;
        const long goff = ((long)(b * 4 + h) * 256 + n) * 64 + dh;

        pass8x8(Wq, zr, ps, kq, ln);
        __syncthreads();
        {
            float4 a = combine8(ps, e);
            float4 bb = *(const float4*)(bq + d0);
            a.x += bb.x; a.y += bb.y; a.z += bb.z; a.w += bb.w;
            *(float4*)(Qg + goff) = a;
        }
        __syncthreads();

        pass8x8(Wk, zr, ps, kq, ln);
        __syncthreads();
        {
            float4 a = combine8(ps, e);
            float4 bb = *(const float4*)(bk + d0);
            a.x += bb.x; a.y += bb.y; a.z += bb.z; a.w += bb.w;
            *(float4*)(Kg + goff) = a;
        }
        __syncthreads();

        pass8x8(Wv, zr, ps, kq, ln);
        __syncthreads();
        {
            float4 a = combine8(ps, e);
            float4 bb = *(const float4*)(bv + d0);
            a.x += bb.x; a.y += bb.y; a.z += bb.z; a.w += bb.w;
            *(float4*)(Vg + goff) = a;
        }
    }
}

// ---------------------------------------------------------------------------
// KB v4: AG-NFA attention. v2 structure + V staged in LDS.
// Grid = 256 = #CUs -> each CU hosts exactly 1 block, so LDS above 70 KB is
// free (occupancy unchanged). V staging converts the PV loop's 256 global
// f4 loads/thread (1:4 VMEM:VALU, 32x duplicated across q) into 8 coalesced
// staging loads + conflict-free LDS broadcasts. All else byte-identical.
// LDS: Kl 68KB + Vl 68KB + k2 1KB = 140 KB.
// ---------------------------------------------------------------------------
__global__ __launch_bounds__(512, 2) void kb_attn(
    const float* __restrict__ Qg, const float* __restrict__ Kg,
    const float* __restrict__ Vg, float* __restrict__ Og)
{
    extern __shared__ float lds[];
    float* Kl = lds;                   // [256][KSTR]
    float* Vl = lds + 256 * KSTR;      // [256][KSTR]
    float* k2 = lds + 2 * 256 * KSTR;  // [256]
    float* Pl = Kl;                    // [32][PSTR] overlay on Kl after QK^T

    const int tid = threadIdx.x;
    const int xcd = blockIdx.x & 7, slot = blockIdx.x >> 3;
    const int bh = xcd * 4 + (slot >> 3);
    const int qt = slot & 7;

    const float* Qb = Qg + (bh * 256 + qt * 32) * 64;
    const float* Kb = Kg + bh * 16384;
    const float* Vb = Vg + bh * 16384;

    const int q = tid >> 4;   // 0..31: query row
    const int r = tid & 15;   // 0..15

    // ---- stage K and V -> LDS (fully coalesced) ----
    {
        const float4* Ks = (const float4*)Kb;
        const float4* Vs = (const float4*)Vb;
        #pragma unroll
        for (int i = 0; i < 8; ++i) {
            int flat = tid + 512 * i;            // f4 index, 4096 total
            int row = flat >> 4, c4 = flat & 15;
            *(float4*)(Kl + row * KSTR + c4 * 4) = Ks[flat];
            *(float4*)(Vl + row * KSTR + c4 * 4) = Vs[flat];
        }
    }
    __syncthreads();

    // ---- k2[m] = |K_m|^2 ----
    {
        int row = tid >> 1, half = tid & 1;
        const float* kp = Kl + row * KSTR + half * 32;
        float ssq = 0.f;
        #pragma unroll
        for (int c = 0; c < 8; ++c) {
            float4 kv = *(const float4*)(kp + 4 * c);
            ssq += kv.x*kv.x + kv.y*kv.y + kv.z*kv.z + kv.w*kv.w;
        }
        ssq += __shfl_xor(ssq, 1);
        if (half == 0) k2[row] = ssq;
    }

    // ---- Q row in registers + NF stats (thread-local) ----
    float4 Qr[16];
    {
        const float4* Qp = (const float4*)(Qb + q * 64);
        #pragma unroll
        for (int c = 0; c < 16; ++c) Qr[c] = Qp[c];
    }
    float fq, gq, iq;
    {
        float s = 0.f, ss = 0.f;
        #pragma unroll
        for (int c = 0; c < 16; ++c) {
            float4 v = Qr[c];
            s  += v.x + v.y + v.z + v.w;
            ss += v.x*v.x + v.y*v.y + v.z*v.z + v.w*v.w;
        }
        float mu = s * (1.f / 64.f);
        float as = 0.f;
        #pragma unroll
        for (int c = 0; c < 16; ++c) {
            float4 v = Qr[c];
            as += fabsf(v.x - mu) + fabsf(v.y - mu)
                + fabsf(v.z - mu) + fabsf(v.w - mu);
        }
        float var = ss * (1.f / 64.f) - mu * mu;
        float sg  = sqrtf(var + EPSF);
        float nf  = as / (sg + EPSF);
        float inv = 1.f / (__expf(-nf) + 1.f);
        fq = 0.125f + 2.f * inv;
        gq = ss * inv;
        iq = inv;
    }
    __syncthreads();   // k2 visible

    // ---- QK^T: scores for m = r + 16j ----
    float s_[16];
    #pragma unroll
    for (int j = 0; j < 16; ++j) {
        int m = r + 16 * j;
        const float* kp = Kl + m * KSTR;
        float acc = 0.f;
        #pragma unroll
        for (int c = 0; c < 16; ++c) {
            float4 kv = *(const float4*)(kp + 4 * c);
            acc += Qr[c].x*kv.x + Qr[c].y*kv.y + Qr[c].z*kv.z + Qr[c].w*kv.w;
        }
        s_[j] = acc * fq - gq - k2[m] * iq;
    }

    // ---- softmax over m ----
    float M = s_[0];
    #pragma unroll
    for (int j = 1; j < 16; ++j) M = fmaxf(M, s_[j]);
    #pragma unroll
    for (int o = 1; o < 16; o <<= 1) M = fmaxf(M, __shfl_xor(M, o));
    float L = 0.f;
    #pragma unroll
    for (int j = 0; j < 16; ++j) { s_[j] = __expf(s_[j] - M); L += s_[j]; }
    #pragma unroll
    for (int o = 1; o < 16; o <<= 1) L += __shfl_xor(L, o);
    float invL = 1.f / L;

    __syncthreads();   // done reading Kl/k2 -> overlay Pl (Vl untouched)
    #pragma unroll
    for (int j = 0; j < 16; ++j) Pl[q * PSTR + r + 16 * j] = s_[j] * invL;
    __syncthreads();

    // ---- PV: thread owns d = 4r..4r+4; V rows read from LDS ----
    float4 a0 = make_float4(0.f, 0.f, 0.f, 0.f);
    const float* pq = Pl + q * PSTR;
    const float* vp = Vl + 4 * r;
    #pragma unroll 8
    for (int m = 0; m < 256; ++m) {
        float pw = pq[m];
        float4 v = *(const float4*)(vp + m * KSTR);
        a0.x = fmaf(pw, v.x, a0.x); a0.y = fmaf(pw, v.y, a0.y);
        a0.z = fmaf(pw, v.z, a0.z); a0.w = fmaf(pw, v.w, a0.w);
    }
    {
        int b = bh >> 2, h = bh & 3;
        int n = qt * 32 + q;
        float* op = Og + (b * 256 + n) * 256 + h * 64 + 4 * r;
        *(float4*)op = a0;
    }
}

// ---------------------------------------------------------------------------
// KC: Y = attn_out @ Wo + bo, then LE-fusion. [R6-verified]
// ---------------------------------------------------------------------------
__global__ __launch_bounds__(512, 2) void kc_wo_le(
    const float* __restrict__ Og, const float* __restrict__ Wo,
    const float* __restrict__ bo, float* __restrict__ out)
{
    extern __shared__ float sm[];
    float* yr  = sm;           // [8][256]
    float* ps  = sm + 2048;    // [8][8][256] (64 KB)
    float* red = sm + 18432;   // [8]

    const int tid = threadIdx.x;
    const int kq = tid >> 6, ln = tid & 63;
    const int wave = tid >> 6, lane = tid & 63;
    const int tok0 = blockIdx.x * 8;

    *(float4*)(yr + tid * 4) = *(const float4*)(Og + tok0 * 256 + tid * 4);
    __syncthreads();

    pass8x8(Wo, yr, ps, kq, ln);
    __syncthreads();
    {
        int e = tid * 4;
        float4 a = combine8(ps, e);
        float4 bb = *(const float4*)(bo + (e & 255));
        a.x += bb.x; a.y += bb.y; a.z += bb.z; a.w += bb.w;
        *(float4*)(yr + e) = a;
    }
    __syncthreads();
    // per-token ||Y||: wave owns token `wave`
    {
        float ssq = 0.f;
        #pragma unroll
        for (int c = 0; c < 4; ++c) {
            float v = yr[wave * 256 + lane + 64 * c];
            ssq += v * v;
        }
        #pragma unroll
        for (int o = 32; o; o >>= 1) ssq += __shfl_xor(ssq, o);
        if (lane == 0) red[wave] = sqrtf(ssq);
    }
    __syncthreads();
    // LE-fusion
    {
        int g = tid >> 8, d = tid & 255;
        float e0 = red[4 * g], e1 = red[4 * g + 1], e2 = red[4 * g + 2], e3 = red[4 * g + 3];
        float m = fmaxf(fmaxf(e0, e1), fmaxf(e2, e3));
        float x0 = __expf(e0 - m), x1 = __expf(e1 - m), x2 = __expf(e2 - m), x3 = __expf(e3 - m);
        float inv = 1.f / (x0 + x1 + x2 + x3);
        float val = (x0 * yr[(4 * g) * 256 + d] + x1 * yr[(4 * g + 1) * 256 + d]
                   + x2 * yr[(4 * g + 2) * 256 + d] + x3 * yr[(4 * g + 3) * 256 + d]) * inv;
        out[(blockIdx.x * 2 + g) * 256 + d] = val;
    }
}

// ---------------------------------------------------------------------------
extern "C" void kernel_launch(void* const* d_in, const int* in_sizes, int n_in,
                              void* d_out, int out_size, void* d_ws, size_t ws_size,
                              hipStream_t stream) {
    const float* x    = (const float*)d_in[0];
    const float* Wp   = (const float*)d_in[1];
    const float* bp   = (const float*)d_in[2];
    const float* ln_g = (const float*)d_in[3];
    const float* ln_b = (const float*)d_in[4];
    const float* Wq   = (const float*)d_in[5];
    const float* bq   = (const float*)d_in[6];
    const float* Wk   = (const float*)d_in[7];
    const float* bk   = (const float*)d_in[8];
    const float* Wv   = (const float*)d_in[9];
    const float* bv   = (const float*)d_in[10];
    const float* Wo   = (const float*)d_in[11];
    const float* bo   = (const float*)d_in[12];
    float* out = (float*)d_out;

    float* ws = (float*)d_ws;
    float* Qg = ws;
    float* Kg = ws + 524288;
    float* Vg = ws + 524288 * 2;
    float* Og = ws + 524288 * 3;

    const int ka_lds = (2048 + 16384) * 4;              // 73728 B
    const int kb_lds = (2 * 256 * KSTR + 256) * 4;      // 140288 B
    const int kc_lds = (2048 + 16384 + 8) * 4;          // 73760 B
    (void)hipFuncSetAttribute((const void*)ka_patch_nf_qkv,
                              hipFuncAttributeMaxDynamicSharedMemorySize, ka_lds);
    (void)hipFuncSetAttribute((const void*)kb_attn,
                              hipFuncAttributeMaxDynamicSharedMemorySize, kb_lds);
    (void)hipFuncSetAttribute((const void*)kc_wo_le,
                              hipFuncAttributeMaxDynamicSharedMemorySize, kc_lds);

    ka_patch_nf_qkv<<<256, 512, ka_lds, stream>>>(x, Wp, bp, ln_g, ln_b,
                                                  Wq, bq, Wk, bk, Wv, bv, Qg, Kg, Vg);
    kb_attn<<<256, 512, kb_lds, stream>>>(Qg, Kg, Vg, Og);
    kc_wo_le<<<256, 512, kc_lds, stream>>>(Og, Wo, bo, out);
}

// Round 8
// 49.727 us; speedup vs baseline: 2.6619x; 1.0038x over previous
//
#include <hip/hip_runtime.h>

#define EPSF 1e-5f
#define KSTR 68    // kb K/V LDS row stride (floats)
#define PSTR 260   // kb P row stride (floats)

#define FMA4(ACC, ZS, WV) \
    ACC.x = fmaf(ZS, WV.x, ACC.x); ACC.y = fmaf(ZS, WV.y, ACC.y); \
    ACC.z = fmaf(ZS, WV.z, ACC.z); ACC.w = fmaf(ZS, WV.w, ACC.w);

// ---------------------------------------------------------------------------
// GEMM pass, 8-token/thread form: thread (kq=tid>>6 in [0,8), ln=tid&63)
// owns k-rows [32kq,32kq+32), ALL 8 tokens, dims [4ln,4ln+4).
// VMEM:VALU instruction ratio 1:32. Partials ps[kq][tok][256] (64 KB).
// [R6-verified]
// ---------------------------------------------------------------------------
__device__ __forceinline__ void pass8x8(
    const float* __restrict__ W, const float* __restrict__ zr,
    float* __restrict__ ps, int kq, int ln)
{
    const float* wr = W + kq * 8192 + 4 * ln;    // k-row base
    const float* zb = zr + kq * 32;
    float4 a0 = make_float4(0.f,0.f,0.f,0.f), a1 = a0, a2 = a0, a3 = a0;
    float4 a4 = a0, a5 = a0, a6 = a0, a7 = a0;
    #pragma unroll
    for (int kk = 0; kk < 32; kk += 4) {
        float4 w0 = *(const float4*)(wr + (kk + 0) * 256);
        float4 w1 = *(const float4*)(wr + (kk + 1) * 256);
        float4 w2 = *(const float4*)(wr + (kk + 2) * 256);
        float4 w3 = *(const float4*)(wr + (kk + 3) * 256);
        float4 z0 = *(const float4*)(zb + 0 * 256 + kk);
        float4 z1 = *(const float4*)(zb + 1 * 256 + kk);
        float4 z2 = *(const float4*)(zb + 2 * 256 + kk);
        float4 z3 = *(const float4*)(zb + 3 * 256 + kk);
        float4 z4 = *(const float4*)(zb + 4 * 256 + kk);
        float4 z5 = *(const float4*)(zb + 5 * 256 + kk);
        float4 z6 = *(const float4*)(zb + 6 * 256 + kk);
        float4 z7 = *(const float4*)(zb + 7 * 256 + kk);
        FMA4(a0, z0.x, w0) FMA4(a0, z0.y, w1) FMA4(a0, z0.z, w2) FMA4(a0, z0.w, w3)
        FMA4(a1, z1.x, w0) FMA4(a1, z1.y, w1) FMA4(a1, z1.z, w2) FMA4(a1, z1.w, w3)
        FMA4(a2, z2.x, w0) FMA4(a2, z2.y, w1) FMA4(a2, z2.z, w2) FMA4(a2, z2.w, w3)
        FMA4(a3, z3.x, w0) FMA4(a3, z3.y, w1) FMA4(a3, z3.z, w2) FMA4(a3, z3.w, w3)
        FMA4(a4, z4.x, w0) FMA4(a4, z4.y, w1) FMA4(a4, z4.z, w2) FMA4(a4, z4.w, w3)
        FMA4(a5, z5.x, w0) FMA4(a5, z5.y, w1) FMA4(a5, z5.z, w2) FMA4(a5, z5.w, w3)
        FMA4(a6, z6.x, w0) FMA4(a6, z6.y, w1) FMA4(a6, z6.z, w2) FMA4(a6, z6.w, w3)
        FMA4(a7, z7.x, w0) FMA4(a7, z7.y, w1) FMA4(a7, z7.z, w2) FMA4(a7, z7.w, w3)
    }
    float* pp = ps + kq * 2048 + 4 * ln;
    *(float4*)(pp + 0 * 256) = a0;
    *(float4*)(pp + 1 * 256) = a1;
    *(float4*)(pp + 2 * 256) = a2;
    *(float4*)(pp + 3 * 256) = a3;
    *(float4*)(pp + 4 * 256) = a4;
    *(float4*)(pp + 5 * 256) = a5;
    *(float4*)(pp + 6 * 256) = a6;
    *(float4*)(pp + 7 * 256) = a7;
}

__device__ __forceinline__ float4 combine8(const float* __restrict__ ps, int e)
{
    float4 a = *(const float4*)(ps + e);
    #pragma unroll
    for (int k = 1; k < 8; ++k) {
        float4 u = *(const float4*)(ps + k * 2048 + e);
        a.x += u.x; a.y += u.y; a.z += u.z; a.w += u.w;
    }
    return a;
}

// ---------------------------------------------------------------------------
// KA v3: patch embed + LN + NF + QKV. 256 blocks x 512 threads.
//  - Double-buffered partials psA/psB (64 KB each; LDS 136 KB is free at
//    1 block/CU): combine of pass k overlaps GEMM of pass k+1 in the same
//    phase -> QKV barriers 6 -> 3, and combine LDS reads + global store
//    hide under the next pass's VMEM/FMA.
//  - In-register LN/NF: combine thread tid holds the 4 elements of token
//    tid>>6 = its own wave's token, so stats are pure wave shuffles; no
//    zr round-trip, one barrier saved.
//  Total barriers 9 -> 6.
// ---------------------------------------------------------------------------
__global__ __launch_bounds__(512, 2) void ka_patch_nf_qkv(
    const float* __restrict__ x,
    const float* __restrict__ Wp, const float* __restrict__ bp,
    const float* __restrict__ ln_g, const float* __restrict__ ln_b,
    const float* __restrict__ Wq, const float* __restrict__ bq,
    const float* __restrict__ Wk, const float* __restrict__ bk,
    const float* __restrict__ Wv, const float* __restrict__ bv,
    float* __restrict__ Qg, float* __restrict__ Kg, float* __restrict__ Vg)
{
    extern __shared__ float sm[];
    float* zr  = sm;           // [8][256] patch rows, then z rows
    float* psA = sm + 2048;    // [8][8][256] (64 KB)
    float* psB = sm + 18432;   // [8][8][256] (64 KB)

    const int tid = threadIdx.x;
    const int kq = tid >> 6, ln = tid & 63;
    const int lane = tid & 63;
    const int tok0 = blockIdx.x * 8;

    // ---- stage 8 patches as rows (float4/thread) ----
    {
        int e = tid * 4;
        int t = e >> 8, dd = e & 255;
        int tk = tok0 + t, b = tk >> 8, n = tk & 255;
        int ph = n >> 4, pw = n & 15, p = (dd >> 4) & 15, q = dd & 15;
        *(float4*)(zr + e) =
            *(const float4*)(x + b * 65536 + (ph * 16 + p) * 256 + pw * 16 + q);
    }
    __syncthreads();

    // ---- pass 0: z = patch @ Wp -> psA ----
    pass8x8(Wp, zr, psA, kq, ln);
    __syncthreads();

    // ---- combine + bias + in-register LN/NF (token = wave) ----
    {
        int e = tid * 4;                       // token tid>>6, dims 4*lane..+4
        float4 a = combine8(psA, e);
        float4 bb = *(const float4*)(bp + 4 * lane);
        a.x += bb.x; a.y += bb.y; a.z += bb.z; a.w += bb.w;

        float s  = a.x + a.y + a.z + a.w;
        float ss = a.x*a.x + a.y*a.y + a.z*a.z + a.w*a.w;
        #pragma unroll
        for (int o = 32; o; o >>= 1) { s += __shfl_xor(s, o); ss += __shfl_xor(ss, o); }
        float mu  = s * (1.f / 256.f);
        float var = ss * (1.f / 256.f) - mu * mu;
        float rs  = rsqrtf(var + EPSF);

        float4 g  = *(const float4*)(ln_g + 4 * lane);
        float4 b2 = *(const float4*)(ln_b + 4 * lane);
        float4 zn;
        zn.x = (a.x - mu) * rs * g.x + b2.x;
        zn.y = (a.y - mu) * rs * g.y + b2.y;
        zn.z = (a.z - mu) * rs * g.z + b2.z;
        zn.w = (a.w - mu) * rs * g.w + b2.w;

        float s2  = zn.x + zn.y + zn.z + zn.w;
        float ss2 = zn.x*zn.x + zn.y*zn.y + zn.z*zn.z + zn.w*zn.w;
        #pragma unroll
        for (int o = 32; o; o >>= 1) { s2 += __shfl_xor(s2, o); ss2 += __shfl_xor(ss2, o); }
        float mu2  = s2 * (1.f / 256.f);
        float var2 = ss2 * (1.f / 256.f) - mu2 * mu2;

        float as = fabsf(zn.x - mu2) + fabsf(zn.y - mu2)
                 + fabsf(zn.z - mu2) + fabsf(zn.w - mu2);
        #pragma unroll
        for (int o = 32; o; o >>= 1) as += __shfl_xor(as, o);
        float nf = as / (sqrtf(var2 + EPSF) + EPSF);
        float sc = 1.f + nf;
        zn.x *= sc; zn.y *= sc; zn.z *= sc; zn.w *= sc;
        *(float4*)(zr + e) = zn;
    }
    __syncthreads();

    // ---- QKV: double-buffered pass/combine pipeline ----
    int e = tid * 4, t = e >> 8, d0 = e & 255;
    int tk = tok0 + t, b = tk >> 8, n = tk & 255;
    int h = d0 >> 6, dh = d0 & 63;
    const long goff = ((long)(b * 4 + h) * 256 + n) * 64 + dh;

    pass8x8(Wq, zr, psB, kq, ln);
    __syncthreads();

    // phase: combine Q (psB) + pass K (psA)
    {
        float4 a = combine8(psB, e);
        float4 bb = *(const float4*)(bq + d0);
        a.x += bb.x; a.y += bb.y; a.z += bb.z; a.w += bb.w;
        *(float4*)(Qg + goff) = a;
    }
    pass8x8(Wk, zr, psA, kq, ln);
    __syncthreads();

    // phase: combine K (psA) + pass V (psB)
    {
        float4 a = combine8(psA, e);
        float4 bb = *(const float4*)(bk + d0);
        a.x += bb.x; a.y += bb.y; a.z += bb.z; a.w += bb.w;
        *(float4*)(Kg + goff) = a;
    }
    pass8x8(Wv, zr, psB, kq, ln);
    __syncthreads();

    // final: combine V (psB)
    {
        float4 a = combine8(psB, e);
        float4 bb = *(const float4*)(bv + d0);
        a.x += bb.x; a.y += bb.y; a.z += bb.z; a.w += bb.w;
        *(float4*)(Vg + goff) = a;
    }
}

// ---------------------------------------------------------------------------
// KB v4: AG-NFA attention — EXACT R7 form (verified -7.6 µs winner).
// K and V staged in LDS (140 KB, free at 1 block/CU); Q + NF in registers.
// ---------------------------------------------------------------------------
__global__ __launch_bounds__(512, 2) void kb_attn(
    const float* __restrict__ Qg, const float* __restrict__ Kg,
    const float* __restrict__ Vg, float* __restrict__ Og)
{
    extern __shared__ float lds[];
    float* Kl = lds;                   // [256][KSTR]
    float* Vl = lds + 256 * KSTR;      // [256][KSTR]
    float* k2 = lds + 2 * 256 * KSTR;  // [256]
    float* Pl = Kl;                    // [32][PSTR] overlay on Kl after QK^T

    const int tid = threadIdx.x;
    const int xcd = blockIdx.x & 7, slot = blockIdx.x >> 3;
    const int bh = xcd * 4 + (slot >> 3);
    const int qt = slot & 7;

    const float* Qb = Qg + (bh * 256 + qt * 32) * 64;
    const float* Kb = Kg + bh * 16384;
    const float* Vb = Vg + bh * 16384;

    const int q = tid >> 4;   // 0..31: query row
    const int r = tid & 15;   // 0..15

    // ---- stage K and V -> LDS (fully coalesced) ----
    {
        const float4* Ks = (const float4*)Kb;
        const float4* Vs = (const float4*)Vb;
        #pragma unroll
        for (int i = 0; i < 8; ++i) {
            int flat = tid + 512 * i;            // f4 index, 4096 total
            int row = flat >> 4, c4 = flat & 15;
            *(float4*)(Kl + row * KSTR + c4 * 4) = Ks[flat];
            *(float4*)(Vl + row * KSTR + c4 * 4) = Vs[flat];
        }
    }
    __syncthreads();

    // ---- k2[m] = |K_m|^2 ----
    {
        int row = tid >> 1, half = tid & 1;
        const float* kp = Kl + row * KSTR + half * 32;
        float ssq = 0.f;
        #pragma unroll
        for (int c = 0; c < 8; ++c) {
            float4 kv = *(const float4*)(kp + 4 * c);
            ssq += kv.x*kv.x + kv.y*kv.y + kv.z*kv.z + kv.w*kv.w;
        }
        ssq += __shfl_xor(ssq, 1);
        if (half == 0) k2[row] = ssq;
    }

    // ---- Q row in registers + NF stats (thread-local) ----
    float4 Qr[16];
    {
        const float4* Qp = (const float4*)(Qb + q * 64);
        #pragma unroll
        for (int c = 0; c < 16; ++c) Qr[c] = Qp[c];
    }
    float fq, gq, iq;
    {
        float s = 0.f, ss = 0.f;
        #pragma unroll
        for (int c = 0; c < 16; ++c) {
            float4 v = Qr[c];
            s  += v.x + v.y + v.z + v.w;
            ss += v.x*v.x + v.y*v.y + v.z*v.z + v.w*v.w;
        }
        float mu = s * (1.f / 64.f);
        float as = 0.f;
        #pragma unroll
        for (int c = 0; c < 16; ++c) {
            float4 v = Qr[c];
            as += fabsf(v.x - mu) + fabsf(v.y - mu)
                + fabsf(v.z - mu) + fabsf(v.w - mu);
        }
        float var = ss * (1.f / 64.f) - mu * mu;
        float sg  = sqrtf(var + EPSF);
        float nf  = as / (sg + EPSF);
        float inv = 1.f / (__expf(-nf) + 1.f);
        fq = 0.125f + 2.f * inv;
        gq = ss * inv;
        iq = inv;
    }
    __syncthreads();   // k2 visible

    // ---- QK^T: scores for m = r + 16j ----
    float s_[16];
    #pragma unroll
    for (int j = 0; j < 16; ++j) {
        int m = r + 16 * j;
        const float* kp = Kl + m * KSTR;
        float acc = 0.f;
        #pragma unroll
        for (int c = 0; c < 16; ++c) {
            float4 kv = *(const float4*)(kp + 4 * c);
            acc += Qr[c].x*kv.x + Qr[c].y*kv.y + Qr[c].z*kv.z + Qr[c].w*kv.w;
        }
        s_[j] = acc * fq - gq - k2[m] * iq;
    }

    // ---- softmax over m ----
    float M = s_[0];
    #pragma unroll
    for (int j = 1; j < 16; ++j) M = fmaxf(M, s_[j]);
    #pragma unroll
    for (int o = 1; o < 16; o <<= 1) M = fmaxf(M, __shfl_xor(M, o));
    float L = 0.f;
    #pragma unroll
    for (int j = 0; j < 16; ++j) { s_[j] = __expf(s_[j] - M); L += s_[j]; }
    #pragma unroll
    for (int o = 1; o < 16; o <<= 1) L += __shfl_xor(L, o);
    float invL = 1.f / L;

    __syncthreads();   // done reading Kl/k2 -> overlay Pl (Vl untouched)
    #pragma unroll
    for (int j = 0; j < 16; ++j) Pl[q * PSTR + r + 16 * j] = s_[j] * invL;
    __syncthreads();

    // ---- PV: thread owns d = 4r..4r+4; V rows read from LDS ----
    float4 a0 = make_float4(0.f, 0.f, 0.f, 0.f);
    const float* pq = Pl + q * PSTR;
    const float* vp = Vl + 4 * r;
    #pragma unroll 8
    for (int m = 0; m < 256; ++m) {
        float pw = pq[m];
        float4 v = *(const float4*)(vp + m * KSTR);
        a0.x = fmaf(pw, v.x, a0.x); a0.y = fmaf(pw, v.y, a0.y);
        a0.z = fmaf(pw, v.z, a0.z); a0.w = fmaf(pw, v.w, a0.w);
    }
    {
        int b = bh >> 2, h = bh & 3;
        int n = qt * 32 + q;
        float* op = Og + (b * 256 + n) * 256 + h * 64 + 4 * r;
        *(float4*)op = a0;
    }
}

// ---------------------------------------------------------------------------
// KC v2: Y = attn_out @ Wo + bo, then LE-fusion. In-register ||Y|| (token =
// wave at the combine), saving one barrier + an LDS round trip.
// ---------------------------------------------------------------------------
__global__ __launch_bounds__(512, 2) void kc_wo_le(
    const float* __restrict__ Og, const float* __restrict__ Wo,
    const float* __restrict__ bo, float* __restrict__ out)
{
    extern __shared__ float sm[];
    float* yr  = sm;           // [8][256]
    float* ps  = sm + 2048;    // [8][8][256] (64 KB)
    float* red = sm + 18432;   // [8]

    const int tid = threadIdx.x;
    const int kq = tid >> 6, ln = tid & 63;
    const int wave = tid >> 6, lane = tid & 63;
    const int tok0 = blockIdx.x * 8;

    *(float4*)(yr + tid * 4) = *(const float4*)(Og + tok0 * 256 + tid * 4);
    __syncthreads();

    pass8x8(Wo, yr, ps, kq, ln);
    __syncthreads();

    // combine + bias + in-register ||Y|| (token = wave), write yr row
    {
        int e = tid * 4;
        float4 a = combine8(ps, e);
        float4 bb = *(const float4*)(bo + 4 * lane);
        a.x += bb.x; a.y += bb.y; a.z += bb.z; a.w += bb.w;
        float ssq = a.x*a.x + a.y*a.y + a.z*a.z + a.w*a.w;
        #pragma unroll
        for (int o = 32; o; o >>= 1) ssq += __shfl_xor(ssq, o);
        if (lane == 0) red[wave] = sqrtf(ssq);
        *(float4*)(yr + e) = a;
    }
    __syncthreads();

    // LE-fusion
    {
        int g = tid >> 8, d = tid & 255;
        float e0 = red[4 * g], e1 = red[4 * g + 1], e2 = red[4 * g + 2], e3 = red[4 * g + 3];
        float m = fmaxf(fmaxf(e0, e1), fmaxf(e2, e3));
        float x0 = __expf(e0 - m), x1 = __expf(e1 - m), x2 = __expf(e2 - m), x3 = __expf(e3 - m);
        float inv = 1.f / (x0 + x1 + x2 + x3);
        float val = (x0 * yr[(4 * g) * 256 + d] + x1 * yr[(4 * g + 1) * 256 + d]
                   + x2 * yr[(4 * g + 2) * 256 + d] + x3 * yr[(4 * g + 3) * 256 + d]) * inv;
        out[(blockIdx.x * 2 + g) * 256 + d] = val;
    }
}

// ---------------------------------------------------------------------------
extern "C" void kernel_launch(void* const* d_in, const int* in_sizes, int n_in,
                              void* d_out, int out_size, void* d_ws, size_t ws_size,
                              hipStream_t stream) {
    const float* x    = (const float*)d_in[0];
    const float* Wp   = (const float*)d_in[1];
    const float* bp   = (const float*)d_in[2];
    const float* ln_g = (const float*)d_in[3];
    const float* ln_b = (const float*)d_in[4];
    const float* Wq   = (const float*)d_in[5];
    const float* bq   = (const float*)d_in[6];
    const float* Wk   = (const float*)d_in[7];
    const float* bk   = (const float*)d_in[8];
    const float* Wv   = (const float*)d_in[9];
    const float* bv   = (const float*)d_in[10];
    const float* Wo   = (const float*)d_in[11];
    const float* bo   = (const float*)d_in[12];
    float* out = (float*)d_out;

    float* ws = (float*)d_ws;
    float* Qg = ws;
    float* Kg = ws + 524288;
    float* Vg = ws + 524288 * 2;
    float* Og = ws + 524288 * 3;

    const int ka_lds = (2048 + 2 * 16384) * 4;          // 139264 B
    const int kb_lds = (2 * 256 * KSTR + 256) * 4;      // 140288 B
    const int kc_lds = (2048 + 16384 + 8) * 4;          // 73760 B
    (void)hipFuncSetAttribute((const void*)ka_patch_nf_qkv,
                              hipFuncAttributeMaxDynamicSharedMemorySize, ka_lds);
    (void)hipFuncSetAttribute((const void*)kb_attn,
                              hipFuncAttributeMaxDynamicSharedMemorySize, kb_lds);
    (void)hipFuncSetAttribute((const void*)kc_wo_le,
                              hipFuncAttributeMaxDynamicSharedMemorySize, kc_lds);

    ka_patch_nf_qkv<<<256, 512, ka_lds, stream>>>(x, Wp, bp, ln_g, ln_b,
                                                  Wq, bq, Wk, bk, Wv, bv, Qg, Kg, Vg);
    kb_attn<<<256, 512, kb_lds, stream>>>(Qg, Kg, Vg, Og);
    kc_wo_le<<<256, 512, kc_lds, stream>>>(Og, Wo, bo, out);
}